// Round 10
// baseline (379.213 us; speedup 1.0000x reference)
//
#include <hip/hip_runtime.h>
#include <math.h>

#define N_NODES 50000
#define N_EDGES 800000
#define FD 128

#define NBUCK 64          // buckets used: dst>>10 -> 0..48
#define BCAP  24576       // entries per bucket (mean 16384, +64 sigma)

// ---- workspace layout (bytes) ----
#define WS_DEG    0u          // int[N]     \  memset [0, 400256)
#define WS_CURSOR 200000u     // int[N]      |
#define WS_BCUR   400000u     // int[64]    /
#define WS_OFF    400256u     // int[N+1] -> 600260
#define WS_AUX    600320u     // int[256]
#define WS_ESRC   601728u     // ushort[E] -> 2201728
#define WS_WT     3801600u    // bf16[8*128*128] -> 4063744
#define WS_HB     16863744u   // bf16[N*128]; ALSO aliased as bin staging (disjoint lifetime)
#define WS_STAGE  16863744u   // uint32[64*24576] = 6.29 MB -> 23155200
#define WS_Q      29663744u   // bf16[N*128]
#define WS_K      42463744u   // fp8[N*128]
#define WS_V      55263744u   // fp8[N*128]
#define WS_S      68063744u   // bf16[N*128], ends 80863744

typedef unsigned short ushort_t;
typedef unsigned int uint_t;
typedef unsigned char uchar_t;
typedef __attribute__((ext_vector_type(8))) short short8;
typedef __attribute__((ext_vector_type(4))) float floatx4;
typedef __attribute__((ext_vector_type(2))) float floatx2;

__device__ __forceinline__ ushort_t f2bf(float f) {
    uint_t u = __float_as_uint(f);
    return (ushort_t)((u + 0x7FFFu + ((u >> 16) & 1u)) >> 16);   // RNE
}
__device__ __forceinline__ float bf2f_lo(uint_t u) { return __uint_as_float(u << 16); }
__device__ __forceinline__ float bf2f_hi(uint_t u) { return __uint_as_float(u & 0xFFFF0000u); }

// ---------------- prep: W->W^T bf16 (blocks 0..63) + edge binning + deg hist (64..) ----------------
__global__ __launch_bounds__(256) void prep_k(
    const float* __restrict__ W0, const float* __restrict__ W1,
    const float* __restrict__ W2, const float* __restrict__ W3,
    const float* __restrict__ W4, const float* __restrict__ W5,
    const float* __restrict__ W6, const float* __restrict__ W7,
    ushort_t* __restrict__ Wt,
    const int* __restrict__ ei, int* __restrict__ deg,
    int* __restrict__ bcur, uint_t* __restrict__ staging)
{
    if (blockIdx.x < 64) {
        const int m = blockIdx.x >> 3;
        const int sl = blockIdx.x & 7;
        const float* W = (m==0)?W0:(m==1)?W1:(m==2)?W2:(m==3)?W3:(m==4)?W4:(m==5)?W5:(m==6)?W6:W7;
        ushort_t* O = Wt + m * (FD * FD);
        #pragma unroll
        for (int it = 0; it < 2; ++it) {
            int i = threadIdx.x + it * 256 + sl * 512;   // 0..4095
            int n = i & 127, k4 = (i >> 7) << 2;
            ushort_t p[4];
            p[0] = f2bf(W[(k4 + 0) * FD + n]);
            p[1] = f2bf(W[(k4 + 1) * FD + n]);
            p[2] = f2bf(W[(k4 + 2) * FD + n]);
            p[3] = f2bf(W[(k4 + 3) * FD + n]);
            *(ushort4*)(O + n * FD + k4) = *(ushort4*)p;   // Wt[n][k]
        }
    } else {
        __shared__ int lhist[NBUCK];
        __shared__ int lbase[NBUCK];
        const int tid = threadIdx.x;
        const int base = (blockIdx.x - 64) * 2048 + tid * 8;   // E % 8 == 0
        if (tid < NBUCK) lhist[tid] = 0;
        __syncthreads();

        uint_t pk[8];
        int li[8];
        const bool act = (base < N_EDGES);
        if (act) {
            int4 s0 = *(const int4*)(ei + base);
            int4 s1 = *(const int4*)(ei + base + 4);
            int4 d0 = *(const int4*)(ei + N_EDGES + base);
            int4 d1 = *(const int4*)(ei + N_EDGES + base + 4);
            int srcs[8] = {s0.x, s0.y, s0.z, s0.w, s1.x, s1.y, s1.z, s1.w};
            int dsts[8] = {d0.x, d0.y, d0.z, d0.w, d1.x, d1.y, d1.z, d1.w};
            #pragma unroll
            for (int j = 0; j < 8; ++j) {
                atomicAdd(&deg[dsts[j]], 1);
                li[j] = atomicAdd(&lhist[dsts[j] >> 10], 1);
                pk[j] = (uint_t)srcs[j] | ((uint_t)dsts[j] << 16);
            }
        }
        __syncthreads();
        if (tid < NBUCK) lbase[tid] = atomicAdd(&bcur[tid], lhist[tid]);
        __syncthreads();
        if (act) {
            #pragma unroll
            for (int j = 0; j < 8; ++j) {
                int bk = pk[j] >> 26;       // dst>>10
                staging[bk * BCAP + lbase[bk] + li[j]] = pk[j];
            }
        }
    }
}

// ---------------- 3-kernel parallel scan ----------------
__global__ __launch_bounds__(256) void scan1_k(const int* __restrict__ deg,
                                               int* __restrict__ off,
                                               int* __restrict__ aux, int n) {
    __shared__ int sbuf[256];
    int tid = threadIdx.x;
    int idx = blockIdx.x * 256 + tid;
    int val = (idx < n) ? deg[idx] : 0;
    sbuf[tid] = val;
    __syncthreads();
    #pragma unroll
    for (int d = 1; d < 256; d <<= 1) {
        int t = (tid >= d) ? sbuf[tid - d] : 0;
        __syncthreads();
        sbuf[tid] += t;
        __syncthreads();
    }
    int incl = sbuf[tid];
    if (idx < n) off[idx] = incl - val;
    if (tid == 255) aux[blockIdx.x] = incl;
}

__global__ __launch_bounds__(256) void scan2_k(int* __restrict__ aux,
                                               int* __restrict__ off,
                                               int nblocks, int n, int total) {
    __shared__ int sbuf[256];
    int tid = threadIdx.x;
    int val = (tid < nblocks) ? aux[tid] : 0;
    sbuf[tid] = val;
    __syncthreads();
    #pragma unroll
    for (int d = 1; d < 256; d <<= 1) {
        int t = (tid >= d) ? sbuf[tid - d] : 0;
        __syncthreads();
        sbuf[tid] += t;
        __syncthreads();
    }
    if (tid < nblocks) aux[tid] = sbuf[tid] - val;
    if (tid == 0) off[n] = total;
}

__global__ __launch_bounds__(256) void scan3_k(int* __restrict__ off,
                                               const int* __restrict__ aux, int n) {
    int idx = blockIdx.x * 256 + threadIdx.x;
    if (idx < n) off[idx] += aux[blockIdx.x];
}

// ---------------- Pass B: per-bucket scatter into CSR (esrc window ~32 KB, L2-hot) ----------------
__global__ __launch_bounds__(256) void binscat_k(
    const uint_t* __restrict__ staging, const int* __restrict__ bcur,
    const int* __restrict__ off, int* __restrict__ cursor,
    ushort_t* __restrict__ esrc)
{
    const int b = blockIdx.x;        // bucket 0..48
    const int part = blockIdx.y;     // 0..7
    const int count = bcur[b];
    const int s = (count * part) >> 3;
    const int e = (count * (part + 1)) >> 3;
    for (int i = s + threadIdx.x; i < e; i += 256) {
        uint_t pkv = staging[b * BCAP + i];
        int src = pkv & 0xFFFFu;
        int dst = pkv >> 16;
        int pos = off[dst] + atomicAdd(&cursor[dst], 1);
        esrc[pos] = (ushort_t)src;
    }
}

// ---------------- MFMA bf16 GEMM: O_m = X @ W_m + b_m, m=0..3 ----------------
// grid ceil(N/64)=782, 256 thr (4 waves). Barrier-free m-loop: per matrix, all
// 32 B-fragments loaded up-front from L2-resident W^T into registers (one
// latency wall, vmcnt-pipelined), 32 back-to-back MFMAs, then a per-wave
// self-contained epilogue through the wave's own 16 LDS rows (within-wave LDS
// RAW needs no barrier). Only one __syncthreads total (after X staging).
__global__ __launch_bounds__(256, 2) void gemm_mfma_k(
    const void* __restrict__ Xin, int x_is_fp32,
    const ushort_t* __restrict__ Wt,
    const float* __restrict__ b0, const float* __restrict__ b1,
    const float* __restrict__ b2, const float* __restrict__ b3,
    ushort_t* __restrict__ Oq, uchar_t* __restrict__ Ok8,
    uchar_t* __restrict__ Ov8, ushort_t* __restrict__ Os, int N)
{
    __shared__ ushort_t As[64][136];    // X tile; reused per-wave as C staging
    const int tid = threadIdx.x;
    const int row0 = blockIdx.x * 64;

    // ---- stage X tile ----
    if (x_is_fp32) {
        const float* Xf = (const float*)Xin;
        #pragma unroll
        for (int it = 0; it < 8; ++it) {
            int i = tid + it * 256;          // 2048 float4 chunks
            int r = i >> 5, c4 = (i & 31) * 4;
            int gr = row0 + r;
            float4 xv = make_float4(0.f, 0.f, 0.f, 0.f);
            if (gr < N) xv = *(const float4*)(Xf + (size_t)gr * FD + c4);
            ushort_t p[4] = {f2bf(xv.x), f2bf(xv.y), f2bf(xv.z), f2bf(xv.w)};
            *(ushort4*)(&As[r][c4]) = *(ushort4*)p;
        }
    } else {
        const ushort_t* Xb = (const ushort_t*)Xin;
        #pragma unroll
        for (int it = 0; it < 4; ++it) {
            int i = tid + it * 256;          // 1024 x 16B chunks
            int r = i >> 4, c8 = (i & 15) * 8;
            int gr = row0 + r;
            uint4 val = make_uint4(0, 0, 0, 0);
            if (gr < N) val = *(const uint4*)(Xb + (size_t)gr * FD + c8);
            *(uint4*)(&As[r][c8]) = val;
        }
    }
    __syncthreads();

    const int wid = tid >> 6, lane = tid & 63;
    const int quad = lane >> 4, col_l = lane & 15;
    const int ar = wid * 16 + col_l;

    // ---- hoist A fragments (invariant across the 4 matrices) ----
    short8 afr[4];
    #pragma unroll
    for (int ks = 0; ks < 4; ++ks)
        afr[ks] = *(const short8*)(&As[ar][ks * 32 + quad * 8]);

    #pragma unroll 1
    for (int m = 0; m < 4; ++m) {
        const ushort_t* Wm = Wt + m * (FD * FD);
        const float* B = (m == 0) ? b0 : (m == 1) ? b1 : (m == 2) ? b2 : b3;

        // ---- load all 32 B-fragments for this matrix into registers ----
        short8 bfr[4][8];
        #pragma unroll
        for (int ks = 0; ks < 4; ++ks)
            #pragma unroll
            for (int nt = 0; nt < 8; ++nt)
                bfr[ks][nt] = *(const short8*)(Wm + (size_t)(nt * 16 + col_l) * FD
                                               + ks * 32 + quad * 8);

        floatx4 acc[8];
        #pragma unroll
        for (int nt = 0; nt < 8; ++nt) acc[nt] = (floatx4){0.f, 0.f, 0.f, 0.f};

        #pragma unroll
        for (int ks = 0; ks < 4; ++ks)
            #pragma unroll
            for (int nt = 0; nt < 8; ++nt)
                acc[nt] = __builtin_amdgcn_mfma_f32_16x16x32_bf16(afr[ks], bfr[ks][nt], acc[nt], 0, 0, 0);

        // ---- per-wave epilogue: C -> own 16 LDS rows, add bias ----
        #pragma unroll
        for (int nt = 0; nt < 8; ++nt) {
            const int col = nt * 16 + col_l;
            const float bv = B[col];
            #pragma unroll
            for (int r = 0; r < 4; ++r)
                As[wid * 16 + quad * 4 + r][col] = f2bf(acc[nt][r] + bv);
        }
        // read back own rows (within-wave LDS RAW: in-order, no barrier needed)
        if (m == 1 || m == 2) {
            uchar_t* O8 = (m == 1) ? Ok8 : Ov8;
            #pragma unroll
            for (int it = 0; it < 4; ++it) {
                int i = lane + it * 64;      // 256 chunks over this wave's 16 rows
                int r = wid * 16 + (i >> 4), c8 = (i & 15) * 8;
                int gr = row0 + r;
                if (gr < N) {
                    uint4 cb = *(const uint4*)(&As[r][c8]);
                    int lo = __builtin_amdgcn_cvt_pk_fp8_f32(bf2f_lo(cb.x), bf2f_hi(cb.x), 0, false);
                    lo = __builtin_amdgcn_cvt_pk_fp8_f32(bf2f_lo(cb.y), bf2f_hi(cb.y), lo, true);
                    int hi = __builtin_amdgcn_cvt_pk_fp8_f32(bf2f_lo(cb.z), bf2f_hi(cb.z), 0, false);
                    hi = __builtin_amdgcn_cvt_pk_fp8_f32(bf2f_lo(cb.w), bf2f_hi(cb.w), hi, true);
                    *(uint2*)(O8 + (size_t)gr * FD + c8) = make_uint2((uint_t)lo, (uint_t)hi);
                }
            }
        } else {
            ushort_t* O = (m == 0) ? Oq : Os;
            #pragma unroll
            for (int it = 0; it < 4; ++it) {
                int i = lane + it * 64;
                int r = wid * 16 + (i >> 4), c8 = (i & 15) * 8;
                int gr = row0 + r;
                if (gr < N) *(uint4*)(O + (size_t)gr * FD + c8) = *(const uint4*)(&As[r][c8]);
            }
        }
    }
}

// ---------------- per-dst attention (16-lane groups, fp8 k+v, packed-f32 math) ----------------
__global__ __launch_bounds__(256) void attn_k(
    const ushort_t* __restrict__ q, const uchar_t* __restrict__ k8,
    const uchar_t* __restrict__ v8, const ushort_t* __restrict__ sp,
    const int* __restrict__ off, const ushort_t* __restrict__ esrc,
    ushort_t* __restrict__ out_bf, float* __restrict__ out_f,
    int relu, int bf16out, int N)
{
    const int wid = threadIdx.x >> 6;
    const int lane = threadIdx.x & 63;
    const int g = lane >> 4;         // edge group 0..3
    const int j = lane & 15;         // lane within group
    const int dst = blockIdx.x * 4 + wid;
    if (dst >= N) return;

    const int beg = off[dst];
    const int end = off[dst + 1];
    const int f0 = j * 8;

    const uint4 qu = *(const uint4*)(q + ((size_t)dst << 7) + f0);
    floatx2 q2[4];
    q2[0] = (floatx2){bf2f_lo(qu.x), bf2f_hi(qu.x)};
    q2[1] = (floatx2){bf2f_lo(qu.y), bf2f_hi(qu.y)};
    q2[2] = (floatx2){bf2f_lo(qu.z), bf2f_hi(qu.z)};
    q2[3] = (floatx2){bf2f_lo(qu.w), bf2f_hi(qu.w)};

    const float scale = 0.08838834764831845f;   // 1/sqrt(128)
    floatx2 lv = (floatx2){0.f, 0.f};
    floatx2 acc2[4];
    #pragma unroll
    for (int i = 0; i < 4; ++i) acc2[i] = (floatx2){0.f, 0.f};

    const int last = end - 1;
    for (int base = beg; base < end; base += 8) {
        const int e0 = base + g;
        const int e1 = base + 4 + g;
        const int i0 = (e0 <= last) ? e0 : last;
        const int i1 = (e1 <= last) ? e1 : last;
        const int s0 = esrc[i0];
        const int s1 = esrc[i1];

        const uint2 k0 = *(const uint2*)(k8 + (size_t)s0 * FD + f0);   // 8 fp8
        const uint2 k1 = *(const uint2*)(k8 + (size_t)s1 * FD + f0);

        floatx2 d0 = __builtin_amdgcn_cvt_pk_f32_fp8(k0.x, false) * q2[0];
        d0 += __builtin_amdgcn_cvt_pk_f32_fp8(k0.x, true)  * q2[1];
        d0 += __builtin_amdgcn_cvt_pk_f32_fp8(k0.y, false) * q2[2];
        d0 += __builtin_amdgcn_cvt_pk_f32_fp8(k0.y, true)  * q2[3];
        float p0 = d0.x + d0.y;

        floatx2 d1 = __builtin_amdgcn_cvt_pk_f32_fp8(k1.x, false) * q2[0];
        d1 += __builtin_amdgcn_cvt_pk_f32_fp8(k1.x, true)  * q2[1];
        d1 += __builtin_amdgcn_cvt_pk_f32_fp8(k1.y, false) * q2[2];
        d1 += __builtin_amdgcn_cvt_pk_f32_fp8(k1.y, true)  * q2[3];
        float p1 = d1.x + d1.y;

        #pragma unroll
        for (int i = 1; i <= 8; i <<= 1) {
            p0 += __shfl_xor(p0, i, 64);
            p1 += __shfl_xor(p1, i, 64);
        }

        float w0 = __expf(p0 * scale);
        float w1 = __expf(p1 * scale);
        if (e0 > last) w0 = 0.f;
        if (e1 > last) w1 = 0.f;

        const uint2 v0 = *(const uint2*)(v8 + (size_t)s0 * FD + f0);   // 8 fp8
        const uint2 v1 = *(const uint2*)(v8 + (size_t)s1 * FD + f0);

        const floatx2 w0v = (floatx2){w0, w0};
        const floatx2 w1v = (floatx2){w1, w1};
        lv += (floatx2){w0, w1};
        acc2[0] += w0v * __builtin_amdgcn_cvt_pk_f32_fp8(v0.x, false);
        acc2[0] += w1v * __builtin_amdgcn_cvt_pk_f32_fp8(v1.x, false);
        acc2[1] += w0v * __builtin_amdgcn_cvt_pk_f32_fp8(v0.x, true);
        acc2[1] += w1v * __builtin_amdgcn_cvt_pk_f32_fp8(v1.x, true);
        acc2[2] += w0v * __builtin_amdgcn_cvt_pk_f32_fp8(v0.y, false);
        acc2[2] += w1v * __builtin_amdgcn_cvt_pk_f32_fp8(v1.y, false);
        acc2[3] += w0v * __builtin_amdgcn_cvt_pk_f32_fp8(v0.y, true);
        acc2[3] += w1v * __builtin_amdgcn_cvt_pk_f32_fp8(v1.y, true);
    }

    float acc[8] = {acc2[0].x, acc2[0].y, acc2[1].x, acc2[1].y,
                    acc2[2].x, acc2[2].y, acc2[3].x, acc2[3].y};
    #pragma unroll
    for (int i = 0; i < 8; ++i) {
        acc[i] += __shfl_xor(acc[i], 16, 64);
        acc[i] += __shfl_xor(acc[i], 32, 64);
    }
    float l = lv.x + lv.y;
    l += __shfl_xor(l, 16, 64);
    l += __shfl_xor(l, 32, 64);

    const float inv = 1.0f / ((l == 0.f) ? 1.f : l);
    const int fo = f0 + g * 2;                          // lane stores 2 feats
    const uint_t su = *(const uint_t*)(sp + ((size_t)dst << 7) + fo);
    float ox = acc[g * 2]     * inv + bf2f_lo(su);
    float oy = acc[g * 2 + 1] * inv + bf2f_hi(su);
    if (relu) { ox = fmaxf(ox, 0.f); oy = fmaxf(oy, 0.f); }
    if (bf16out) {
        ushort_t p2[2] = {f2bf(ox), f2bf(oy)};
        *(uint_t*)(out_bf + ((size_t)dst << 7) + fo) = *(uint_t*)p2;
    } else {
        *(float2*)(out_f + ((size_t)dst << 7) + fo) = make_float2(ox, oy);
    }
}

// ---------------- launch ----------------
extern "C" void kernel_launch(void* const* d_in, const int* in_sizes, int n_in,
                              void* d_out, int out_size, void* d_ws, size_t ws_size,
                              hipStream_t stream) {
    const float* x  = (const float*)d_in[0];
    const int*   ei = (const int*)d_in[1];   // [2,E]: row0=src, row1=dst
    const float* Wq1 = (const float*)d_in[2],  *bq1 = (const float*)d_in[3];
    const float* Wk1 = (const float*)d_in[4],  *bk1 = (const float*)d_in[5];
    const float* Wv1 = (const float*)d_in[6],  *bv1 = (const float*)d_in[7];
    const float* Ws1 = (const float*)d_in[8],  *bs1 = (const float*)d_in[9];
    const float* Wq2 = (const float*)d_in[10], *bq2 = (const float*)d_in[11];
    const float* Wk2 = (const float*)d_in[12], *bk2 = (const float*)d_in[13];
    const float* Wv2 = (const float*)d_in[14], *bv2 = (const float*)d_in[15];
    const float* Ws2 = (const float*)d_in[16], *bs2 = (const float*)d_in[17];

    char* ws = (char*)d_ws;
    int* deg     = (int*)(ws + WS_DEG);
    int* cursor  = (int*)(ws + WS_CURSOR);
    int* bcur    = (int*)(ws + WS_BCUR);
    int* off     = (int*)(ws + WS_OFF);
    int* aux     = (int*)(ws + WS_AUX);
    ushort_t* esrc = (ushort_t*)(ws + WS_ESRC);
    ushort_t* wt = (ushort_t*)(ws + WS_WT);
    uint_t* staging = (uint_t*)(ws + WS_STAGE);
    ushort_t* hb = (ushort_t*)(ws + WS_HB);
    ushort_t* q  = (ushort_t*)(ws + WS_Q);
    uchar_t*  k8 = (uchar_t*)(ws + WS_K);
    uchar_t*  v8 = (uchar_t*)(ws + WS_V);
    ushort_t* s  = (ushort_t*)(ws + WS_S);
    float* out = (float*)d_out;

    const int gblocks = (N_NODES + 63) / 64;          // 782
    const int attn_blocks = (N_NODES + 3) / 4;        // 12500
    const int sblocks = (N_NODES + 255) / 256;        // 196
    const int binblocks = (N_EDGES + 2047) / 2048;    // 391

    // zero deg + cursor + bucket cursors
    hipMemsetAsync(ws + WS_DEG, 0, 400256, stream);

    // fused: weight transpose (blocks 0..63) + edge binning + deg hist (64..)
    prep_k<<<64 + binblocks, 256, 0, stream>>>(Wq1, Wk1, Wv1, Ws1, Wq2, Wk2, Wv2, Ws2,
                                               wt, ei, deg, bcur, staging);

    // parallel scan -> off[]
    scan1_k<<<sblocks, 256, 0, stream>>>(deg, off, aux, N_NODES);
    scan2_k<<<1, 256, 0, stream>>>(aux, off, sblocks, N_NODES, N_EDGES);
    scan3_k<<<sblocks, 256, 0, stream>>>(off, aux, N_NODES);

    // bucketed CSR scatter (writes land in ~32 KB L2-hot windows)
    binscat_k<<<dim3(49, 8), 256, 0, stream>>>(staging, bcur, off, cursor, esrc);

    // layer 1 (fp32 x, converted during staging)
    gemm_mfma_k<<<gblocks, 256, 0, stream>>>(x, 1, wt, bq1, bk1, bv1, bs1,
                                             q, k8, v8, s, N_NODES);
    attn_k<<<attn_blocks, 256, 0, stream>>>(q, k8, v8, s, off, esrc, hb, nullptr,
                                            1, 1, N_NODES);

    // layer 2 (bf16 h)
    gemm_mfma_k<<<gblocks, 256, 0, stream>>>(hb, 0, wt + 4 * FD * FD, bq2, bk2, bv2, bs2,
                                             q, k8, v8, s, N_NODES);
    attn_k<<<attn_blocks, 256, 0, stream>>>(q, k8, v8, s, off, esrc, nullptr, out,
                                            0, 0, N_NODES);
}